// Round 13
// baseline (11653.753 us; speedup 1.0000x reference)
//
#include <hip/hip_runtime.h>

// DKVMN forward, round 13 — table-driven; demand-proof in-register recurrence.
// R9-R12 lesson: the allocator never grants >96 VGPRs for this kernel shape
// (observed grants 56-96 regardless of waves_per_eu/LDS hints), so m[16]
// (64 regs + ~50 working) ALWAYS spills. R13 stops fighting: wave owns 8 rows
// (m[8]=32 regs, total demand ~54 <= the stingiest grant ever observed), so
// the recurrence is spill-free by construction.
//   kW: wtab[513][512] fp32    kG: etab/atab[1025][256] fp32   (3.2 MB, hot)
//   kS: 2048 blocks (b x 8 row-chunks) x 512 thr (8 waves x 8 rows x float4);
//       w via SGPR loads from wtab; e/a LDS tiles per 16 steps; r merged via
//       lane-plane LDS adds, drained with global fp32 atomics (order rotated
//       per chunk to decorrelate line contention).
//   kM: MLP over all 131072 (b,t); vectorized W1 staging.
// ws = 3.2 MB + 128 MiB fp32 r.

#define B_ 256
#define T_ 512
#define N_ 512
#define DK_ 64
#define DV_ 256
#define S_ 64
#define NP_ (B_ * T_)
#define NCID 513
#define NIID 1025
#define TB_ 16
#define CH_ 8   // row-chunks per batch
#define RW_ 8   // rows per wave

typedef _Float16 h16;
typedef __attribute__((ext_vector_type(4))) _Float16 half4;

__device__ __forceinline__ float dot4(float4 a, float4 b) {
  return a.x * b.x + a.y * b.y + a.z * b.z + a.w * b.w;
}
__device__ __forceinline__ float4 h2f(half4 h) {
  return make_float4((float)h.x, (float)h.y, (float)h.z, (float)h.w);
}

// ============ kW: wtab[c][n] = softmax_n(q_c . K_n), 513 blocks ============
__global__ __launch_bounds__(512) void kW(const float* __restrict__ Kmem,
                                          const float* __restrict__ cemb,
                                          float* __restrict__ wtab) {
  __shared__ float s_q[DK_];
  __shared__ float s_red[16];
  const int tid = threadIdx.x, c = blockIdx.x;
  if (tid < DK_) s_q[tid] = c ? cemb[c * DK_ + tid] : 0.f;
  __syncthreads();
  const int n = tid;
  const float4* kr = (const float4*)(Kmem + n * DK_);
  float acc = 0.f;
#pragma unroll
  for (int kk = 0; kk < DK_ / 4; ++kk) acc += dot4(kr[kk], *(const float4*)&s_q[kk * 4]);
  const int lane = tid & 63, wid = tid >> 6;
  float mx = acc;
  for (int off = 32; off; off >>= 1) mx = fmaxf(mx, __shfl_xor(mx, off, 64));
  if (lane == 0) s_red[wid] = mx;
  __syncthreads();
  float gmx = s_red[0];
#pragma unroll
  for (int i = 1; i < 8; ++i) gmx = fmaxf(gmx, s_red[i]);
  const float e = expf(acc - gmx);
  float sum = e;
  for (int off = 32; off; off >>= 1) sum += __shfl_xor(sum, off, 64);
  if (lane == 0) s_red[8 + wid] = sum;
  __syncthreads();
  float gs = 0.f;
#pragma unroll
  for (int i = 0; i < 8; ++i) gs += s_red[8 + i];
  wtab[c * N_ + n] = e / gs;
}

// ============ kG: etab/atab[id][d], 129 blocks x 8 ids =====================
__global__ __launch_bounds__(512) void kG(const float* __restrict__ iemb,
                                          const float* __restrict__ We,
                                          const float* __restrict__ be,
                                          const float* __restrict__ Wa,
                                          const float* __restrict__ ba,
                                          float* __restrict__ etab,
                                          float* __restrict__ atab) {
  __shared__ float s_v[8 * DV_];
  const int tid = threadIdx.x, bi = blockIdx.x;
  {
    const int j = tid >> 6, c4 = tid & 63;
    const int id = bi * 8 + j;
    float4 v = make_float4(0.f, 0.f, 0.f, 0.f);
    if (id >= 1 && id < NIID) v = ((const float4*)iemb)[(size_t)id * 64 + c4];
    *(float4*)&s_v[j * DV_ + c4 * 4] = v;
  }
  __syncthreads();
  const int gate = tid >> 8, d = tid & 255;
  const float4* wr = (const float4*)((gate ? Wa : We) + d * DV_);
  float acc[8];
#pragma unroll
  for (int j = 0; j < 8; ++j) acc[j] = 0.f;
  for (int kk = 0; kk < DV_ / 4; ++kk) {
    const float4 w4 = wr[kk];
#pragma unroll
    for (int j = 0; j < 8; ++j) acc[j] += dot4(w4, *(const float4*)&s_v[j * DV_ + kk * 4]);
  }
  const float bias = gate ? ba[d] : be[d];
#pragma unroll
  for (int j = 0; j < 8; ++j) {
    const int id = bi * 8 + j;
    if (id < NIID) {
      if (gate) atab[(size_t)id * DV_ + d] = tanhf(acc[j] + bias);
      else      etab[(size_t)id * DV_ + d] = 1.f / (1.f + expf(-(acc[j] + bias)));
    }
  }
}

// ============ kS: in-register recurrence, 2048 blocks x 512 thr ============
// block = (b, ch in 0..7); wave owns 8 rows x float4(lane): m[8] = 32 VGPRs.
__global__ __launch_bounds__(512) void kS(
    const int* __restrict__ concepts, const int* __restrict__ inter,
    const float* __restrict__ Vmem, const float* __restrict__ wtab,
    const float* __restrict__ etab, const float* __restrict__ atab,
    float* __restrict__ r) {
  __shared__ float s_e[TB_][DV_];     // 16 KB
  __shared__ float s_a[TB_][DV_];     // 16 KB
  __shared__ float s_rt[TB_][4][64];  // 16 KB, lane-indexed planes
  const int tid = threadIdx.x, bx = blockIdx.x;
  const int b = bx >> 3, ch = bx & 7;
  const int lane = tid & 63, wv = tid >> 6;
  const int row0 = ch * 64 + __builtin_amdgcn_readfirstlane(wv * RW_);
  float4 m[RW_];  // 32 VGPRs of true state, resident for all 512 steps
  {
    const float4* vm4 = (const float4*)Vmem;
#pragma unroll
    for (int i = 0; i < RW_; ++i) m[i] = vm4[(size_t)(row0 + i) * 64 + lane];
  }
  const int* cb = concepts + b * T_;
  const int* ib = inter + b * T_;
  const float4* etab4 = (const float4*)etab;
  const float4* atab4 = (const float4*)atab;
  float* rb = r + (size_t)b * T_ * DV_;

  for (int t0 = 0; t0 < T_; t0 += TB_) {
    // ---- stage e/a tiles (block-uniform ids, coalesced); zero r planes ----
#pragma unroll
    for (int i = 0; i < 4; ++i) {
      const int idx = tid + i * 512;  // 0..2047 float4
      const int tl = idx >> 7, half = (idx >> 6) & 1, c4 = idx & 63;
      const int iv = ib[t0 + tl];
      if (half == 0)
        *(float4*)&s_e[tl][c4 * 4] = etab4[(size_t)iv * 64 + c4];
      else
        *(float4*)&s_a[tl][c4 * 4] = atab4[(size_t)iv * 64 + c4];
    }
#pragma unroll
    for (int i = 0; i < 2; ++i)
      ((float4*)s_rt)[tid + i * 512] = make_float4(0.f, 0.f, 0.f, 0.f);
    __syncthreads();

    // ---- 16 timesteps over register-resident state ----
    for (int tl = 0; tl < TB_; ++tl) {
      // wave-uniform w: scalar loads (SGPR-held), zero LDS
      const float* wp = wtab + (size_t)cb[t0 + tl] * N_ + row0;
      const float4 w0 = *(const float4*)(wp + 0);
      const float4 w1 = *(const float4*)(wp + 4);
      const float4 e4 = *(const float4*)&s_e[tl][lane * 4];
      const float4 a4 = *(const float4*)&s_a[tl][lane * 4];
      float4 racc = make_float4(0.f, 0.f, 0.f, 0.f);
#pragma unroll
      for (int i = 0; i < RW_; ++i) {
        const float w = (i < 4) ? ((i == 0) ? w0.x : (i == 1) ? w0.y : (i == 2) ? w0.z : w0.w)
                                : ((i == 4) ? w1.x : (i == 5) ? w1.y : (i == 6) ? w1.z : w1.w);
        racc.x = fmaf(w, m[i].x, racc.x);
        racc.y = fmaf(w, m[i].y, racc.y);
        racc.z = fmaf(w, m[i].z, racc.z);
        racc.w = fmaf(w, m[i].w, racc.w);
        m[i].x = fmaf(-w, fmaf(e4.x, m[i].x, -a4.x), m[i].x);
        m[i].y = fmaf(-w, fmaf(e4.y, m[i].y, -a4.y), m[i].y);
        m[i].z = fmaf(-w, fmaf(e4.z, m[i].z, -a4.z), m[i].z);
        m[i].w = fmaf(-w, fmaf(e4.w, m[i].w, -a4.w), m[i].w);
      }
      // lane-indexed LDS adds: 64 distinct dword addresses (2-way alias, free)
      atomicAdd(&s_rt[tl][0][lane], racc.x);
      atomicAdd(&s_rt[tl][1][lane], racc.y);
      atomicAdd(&s_rt[tl][2][lane], racc.z);
      atomicAdd(&s_rt[tl][3][lane], racc.w);
    }
    __syncthreads();

    // ---- drain: global fp32 atomics; tl order rotated per chunk ----
#pragma unroll
    for (int pass = 0; pass < 2; ++pass) {
      const int tl = (((tid >> 6) + pass * 8) + ch * 2) & 15;
      const int l = tid & 63;
      float* rp = rb + (size_t)(t0 + tl) * DV_ + l * 4;
      atomicAdd(rp + 0, s_rt[tl][0][l]);
      atomicAdd(rp + 1, s_rt[tl][1][l]);
      atomicAdd(rp + 2, s_rt[tl][2][l]);
      atomicAdd(rp + 3, s_rt[tl][3][l]);
    }
    __syncthreads();
  }
}

// ============ kM: MLP head, 2048 blocks x 512 thr ==========================
#define MP_ 64
__global__ __launch_bounds__(512) void kM(const int* __restrict__ concepts,
                                          const float* __restrict__ cemb,
                                          const float* __restrict__ r,
                                          const float* __restrict__ W1,
                                          const float* __restrict__ b1,
                                          const float* __restrict__ W2,
                                          const float* __restrict__ b2,
                                          const float* __restrict__ W3,
                                          const float* __restrict__ b3,
                                          float* __restrict__ out) {
  __shared__ float s_f[MP_][DV_ + DK_];  // 80 KB
  __shared__ h16 s_W1[S_][324];          // 40.5 KB (padded)
  __shared__ float s_h1[8][8][S_];       // 16 KB
  __shared__ int s_c[MP_];
  const int tid = threadIdx.x, g = blockIdx.x;
  const int lane = tid & 63, wv = tid >> 6;
  if (tid < MP_) s_c[tid] = concepts[g * MP_ + tid];
  {
    // vectorized W1 staging: thread (j = tid>>3) loads 10 float4 of row j
    const int j = tid >> 3, f0 = tid & 7;
    const float4* w1r = (const float4*)(W1 + j * 320);
#pragma unroll
    for (int i = 0; i < 10; ++i) {
      const int k4 = f0 + i * 8;
      const float4 v = w1r[k4];
      half4 h;
      h.x = (h16)v.x; h.y = (h16)v.y; h.z = (h16)v.z; h.w = (h16)v.w;
      *(half4*)&s_W1[j][k4 * 4] = h;
    }
  }
  __syncthreads();
  {
    const float4* r4 = (const float4*)r;
#pragma unroll
    for (int i = 0; i < 8; ++i) {
      const int idx = tid + i * 512, p = idx >> 6, c4 = idx & 63;
      *(float4*)&s_f[p][c4 * 4] = r4[(size_t)(g * MP_ + p) * 64 + c4];
    }
    const float4* ce4 = (const float4*)cemb;
    const float4 z = make_float4(0.f, 0.f, 0.f, 0.f);
#pragma unroll
    for (int i = 0; i < 2; ++i) {
      const int idx = tid + i * 512, p = idx >> 4, k4 = idx & 15;
      const int c = s_c[p];
      *(float4*)&s_f[p][DV_ + k4 * 4] = c ? ce4[c * 16 + k4] : z;
    }
  }
  __syncthreads();
  const int j = lane;
  float acc[8];
  {
    const float b1j = b1[j];
#pragma unroll
    for (int p = 0; p < 8; ++p) acc[p] = b1j;
  }
  for (int k4 = 0; k4 < 80; ++k4) {
    const float4 w4 = h2f(*(const half4*)&s_W1[j][k4 * 4]);
#pragma unroll
    for (int p = 0; p < 8; ++p)
      acc[p] += dot4(w4, *(const float4*)&s_f[wv * 8 + p][k4 * 4]);
  }
#pragma unroll
  for (int p = 0; p < 8; ++p) s_h1[wv][p][j] = fmaxf(acc[p], 0.f);
  __syncthreads();
  {
    const float b2j = b2[j];
#pragma unroll
    for (int p = 0; p < 8; ++p) acc[p] = b2j;
  }
  const float4* w2r = (const float4*)(W2 + j * S_);
#pragma unroll
  for (int k4 = 0; k4 < S_ / 4; ++k4) {
    const float4 w4 = w2r[k4];
#pragma unroll
    for (int p = 0; p < 8; ++p)
      acc[p] += dot4(w4, *(const float4*)&s_h1[wv][p][k4 * 4]);
  }
  const float w3j = W3[j], b3v = b3[0];
#pragma unroll
  for (int p = 0; p < 8; ++p) {
    float pp = fmaxf(acc[p], 0.f) * w3j;
    for (int off = 32; off; off >>= 1) pp += __shfl_xor(pp, off, 64);
    if (lane == 0)
      out[g * MP_ + wv * 8 + p] = 1.f / (1.f + expf(-(pp + b3v)));
  }
}

extern "C" void kernel_launch(void* const* d_in, const int* in_sizes, int n_in,
                              void* d_out, int out_size, void* d_ws, size_t ws_size,
                              hipStream_t stream) {
  const int* concepts = (const int*)d_in[0];
  const int* interactions = (const int*)d_in[1];
  const float* Kmem = (const float*)d_in[2];
  const float* Vmem = (const float*)d_in[3];
  const float* cemb = (const float*)d_in[4];
  const float* iemb = (const float*)d_in[5];
  const float* We = (const float*)d_in[6];
  const float* be = (const float*)d_in[7];
  const float* Wa = (const float*)d_in[8];
  const float* ba = (const float*)d_in[9];
  const float* W1 = (const float*)d_in[10];
  const float* b1 = (const float*)d_in[11];
  const float* W2 = (const float*)d_in[12];
  const float* b2 = (const float*)d_in[13];
  const float* W3 = (const float*)d_in[14];
  const float* b3 = (const float*)d_in[15];
  float* out = (float*)d_out;

  const size_t sz_w = (size_t)NCID * N_ * 4;
  const size_t sz_e = (size_t)NIID * DV_ * 4;
  const size_t sz_r = (size_t)NP_ * DV_ * 4;  // 128 MiB
  float* wtab = (float*)d_ws;
  float* etab = (float*)((char*)d_ws + sz_w);
  float* atab = (float*)((char*)d_ws + sz_w + sz_e);
  float* r    = (float*)((char*)d_ws + sz_w + 2 * sz_e);

  kW<<<dim3(NCID), dim3(512), 0, stream>>>(Kmem, cemb, wtab);
  kG<<<dim3((NIID + 7) / 8), dim3(512), 0, stream>>>(iemb, We, be, Wa, ba, etab, atab);
  hipMemsetAsync(r, 0, sz_r, stream);
  kS<<<dim3(B_ * CH_), dim3(512), 0, stream>>>(concepts, interactions, Vmem,
                                               wtab, etab, atab, r);
  kM<<<dim3(NP_ / MP_), dim3(512), 0, stream>>>(concepts, cemb, r,
                                                W1, b1, W2, b2, W3, b3, out);
}

// Round 14
// 6200.836 us; speedup vs baseline: 1.8794x; 1.8794x over previous
//
#include <hip/hip_runtime.h>

// DKVMN forward, round 14 — table-driven; hybrid reg+LDS state, atomic-free.
// R8/R13 measured: global fp32 atomicAdd tops out ~24 G/s device-wide; the r
// drain (134-268M atomics) has been kS's wall since R8. R14 eliminates it:
// 2 row-chunks of 256 rows, each block drains NON-atomic fp16 partials to its
// own 64 MiB region (2 regions fit the ~256 MiB ws; 4+ would not).
// 256 rows/block needs 16 rows/wave; all-register m[16] spills at the ~56-reg
// grant (R9/R11/R12), so: 8 rows in VGPRs (m[8]=32 regs, demand ~56) + 8 rows
// as fp16 in wave-private LDS (64 KB, ds_read/write_b64 per lane).
//   kW: wtab[513][512] fp32   kG: etab/atab[1025][256] fp32   (3.2 MB, hot)
//   kS: 512 blocks (b x 2 chunks) x 1024 thr (16 waves x 16 rows x float4);
//       w via SGPR loads from wtab; e/a LDS tiles per 16 steps; r merged via
//       lane-plane LDS adds, drained as plain fp16 stores (67M total).
//   kM: MLP over all 131072 (b,t); sums the 2 fp16 partial regions.
// ws = 3.2 MB + 128 MiB.

#define B_ 256
#define T_ 512
#define N_ 512
#define DK_ 64
#define DV_ 256
#define S_ 64
#define NP_ (B_ * T_)
#define NCID 513
#define NIID 1025
#define TB_ 16

typedef _Float16 h16;
typedef __attribute__((ext_vector_type(4))) _Float16 half4;

__device__ __forceinline__ float dot4(float4 a, float4 b) {
  return a.x * b.x + a.y * b.y + a.z * b.z + a.w * b.w;
}
__device__ __forceinline__ float4 h2f(half4 h) {
  return make_float4((float)h.x, (float)h.y, (float)h.z, (float)h.w);
}
__device__ __forceinline__ half4 f2h(float4 f) {
  half4 h;
  h.x = (h16)f.x; h.y = (h16)f.y; h.z = (h16)f.z; h.w = (h16)f.w;
  return h;
}

// ============ kW: wtab[c][n] = softmax_n(q_c . K_n), 513 blocks ============
__global__ __launch_bounds__(512) void kW(const float* __restrict__ Kmem,
                                          const float* __restrict__ cemb,
                                          float* __restrict__ wtab) {
  __shared__ float s_q[DK_];
  __shared__ float s_red[16];
  const int tid = threadIdx.x, c = blockIdx.x;
  if (tid < DK_) s_q[tid] = c ? cemb[c * DK_ + tid] : 0.f;
  __syncthreads();
  const int n = tid;
  const float4* kr = (const float4*)(Kmem + n * DK_);
  float acc = 0.f;
#pragma unroll
  for (int kk = 0; kk < DK_ / 4; ++kk) acc += dot4(kr[kk], *(const float4*)&s_q[kk * 4]);
  const int lane = tid & 63, wid = tid >> 6;
  float mx = acc;
  for (int off = 32; off; off >>= 1) mx = fmaxf(mx, __shfl_xor(mx, off, 64));
  if (lane == 0) s_red[wid] = mx;
  __syncthreads();
  float gmx = s_red[0];
#pragma unroll
  for (int i = 1; i < 8; ++i) gmx = fmaxf(gmx, s_red[i]);
  const float e = expf(acc - gmx);
  float sum = e;
  for (int off = 32; off; off >>= 1) sum += __shfl_xor(sum, off, 64);
  if (lane == 0) s_red[8 + wid] = sum;
  __syncthreads();
  float gs = 0.f;
#pragma unroll
  for (int i = 0; i < 8; ++i) gs += s_red[8 + i];
  wtab[c * N_ + n] = e / gs;
}

// ============ kG: etab/atab[id][d], 129 blocks x 8 ids =====================
__global__ __launch_bounds__(512) void kG(const float* __restrict__ iemb,
                                          const float* __restrict__ We,
                                          const float* __restrict__ be,
                                          const float* __restrict__ Wa,
                                          const float* __restrict__ ba,
                                          float* __restrict__ etab,
                                          float* __restrict__ atab) {
  __shared__ float s_v[8 * DV_];
  const int tid = threadIdx.x, bi = blockIdx.x;
  {
    const int j = tid >> 6, c4 = tid & 63;
    const int id = bi * 8 + j;
    float4 v = make_float4(0.f, 0.f, 0.f, 0.f);
    if (id >= 1 && id < NIID) v = ((const float4*)iemb)[(size_t)id * 64 + c4];
    *(float4*)&s_v[j * DV_ + c4 * 4] = v;
  }
  __syncthreads();
  const int gate = tid >> 8, d = tid & 255;
  const float4* wr = (const float4*)((gate ? Wa : We) + d * DV_);
  float acc[8];
#pragma unroll
  for (int j = 0; j < 8; ++j) acc[j] = 0.f;
  for (int kk = 0; kk < DV_ / 4; ++kk) {
    const float4 w4 = wr[kk];
#pragma unroll
    for (int j = 0; j < 8; ++j) acc[j] += dot4(w4, *(const float4*)&s_v[j * DV_ + kk * 4]);
  }
  const float bias = gate ? ba[d] : be[d];
#pragma unroll
  for (int j = 0; j < 8; ++j) {
    const int id = bi * 8 + j;
    if (id < NIID) {
      if (gate) atab[(size_t)id * DV_ + d] = tanhf(acc[j] + bias);
      else      etab[(size_t)id * DV_ + d] = 1.f / (1.f + expf(-(acc[j] + bias)));
    }
  }
}

// ============ kS: hybrid recurrence, 512 blocks x 1024 thr =================
// block = (b, ch in {0,1}); wave owns 16 rows: 8 in VGPRs + 8 fp16 in LDS.
__global__ __launch_bounds__(1024) void kS(
    const int* __restrict__ concepts, const int* __restrict__ inter,
    const float* __restrict__ Vmem, const float* __restrict__ wtab,
    const float* __restrict__ etab, const float* __restrict__ atab,
    h16* __restrict__ rpart) {
  __shared__ half4 s_m[16][8][64];    // 64 KB: wave-private fp16 state rows
  __shared__ float s_e[TB_][DV_];     // 16 KB
  __shared__ float s_a[TB_][DV_];     // 16 KB
  __shared__ float s_rt[TB_][4][64];  // 16 KB, lane-indexed planes
  const int tid = threadIdx.x, bx = blockIdx.x;
  const int b = bx >> 1, ch = bx & 1;
  const int lane = tid & 63, wv = tid >> 6;  // 16 waves
  const int row0 = ch * 256 + __builtin_amdgcn_readfirstlane(wv * 16);
  float4 m[8];  // 32 VGPRs: rows row0..row0+7, fp32, resident 512 steps
  {
    const float4* vm4 = (const float4*)Vmem;
#pragma unroll
    for (int i = 0; i < 8; ++i) m[i] = vm4[(size_t)(row0 + i) * 64 + lane];
    // LDS rows row0+8..row0+15 (fp16)
#pragma unroll
    for (int j = 0; j < 8; ++j)
      s_m[wv][j][lane] = f2h(vm4[(size_t)(row0 + 8 + j) * 64 + lane]);
  }
  const int* cb = concepts + b * T_;
  const int* ib = inter + b * T_;
  const float4* etab4 = (const float4*)etab;
  const float4* atab4 = (const float4*)atab;
  h16* rp = rpart + (size_t)ch * NP_ * DV_ + (size_t)b * T_ * DV_;

  for (int t0 = 0; t0 < T_; t0 += TB_) {
    // ---- stage e/a tiles; zero r planes ----
#pragma unroll
    for (int i = 0; i < 2; ++i) {
      const int idx = tid + i * 1024;  // 0..2047 float4
      const int tl = idx >> 7, half = (idx >> 6) & 1, c4 = idx & 63;
      const int iv = ib[t0 + tl];
      if (half == 0)
        *(float4*)&s_e[tl][c4 * 4] = etab4[(size_t)iv * 64 + c4];
      else
        *(float4*)&s_a[tl][c4 * 4] = atab4[(size_t)iv * 64 + c4];
    }
    ((float4*)s_rt)[tid] = make_float4(0.f, 0.f, 0.f, 0.f);
    __syncthreads();

    // ---- 16 timesteps ----
    for (int tl = 0; tl < TB_; ++tl) {
      // wave-uniform w for 16 rows: scalar loads (SGPR-held)
      const float* wp = wtab + (size_t)cb[t0 + tl] * N_ + row0;
      const float4 w0 = *(const float4*)(wp + 0);
      const float4 w1 = *(const float4*)(wp + 4);
      const float4 w2 = *(const float4*)(wp + 8);
      const float4 w3 = *(const float4*)(wp + 12);
      const float4 e4 = *(const float4*)&s_e[tl][lane * 4];
      const float4 a4 = *(const float4*)&s_a[tl][lane * 4];
      float4 racc = make_float4(0.f, 0.f, 0.f, 0.f);
      // --- 8 register rows ---
#pragma unroll
      for (int i = 0; i < 8; ++i) {
        const float w = (i < 4) ? ((i == 0) ? w0.x : (i == 1) ? w0.y : (i == 2) ? w0.z : w0.w)
                                : ((i == 4) ? w1.x : (i == 5) ? w1.y : (i == 6) ? w1.z : w1.w);
        racc.x = fmaf(w, m[i].x, racc.x);
        racc.y = fmaf(w, m[i].y, racc.y);
        racc.z = fmaf(w, m[i].z, racc.z);
        racc.w = fmaf(w, m[i].w, racc.w);
        m[i].x = fmaf(-w, fmaf(e4.x, m[i].x, -a4.x), m[i].x);
        m[i].y = fmaf(-w, fmaf(e4.y, m[i].y, -a4.y), m[i].y);
        m[i].z = fmaf(-w, fmaf(e4.z, m[i].z, -a4.z), m[i].z);
        m[i].w = fmaf(-w, fmaf(e4.w, m[i].w, -a4.w), m[i].w);
      }
      // --- 8 LDS rows (fp16 storage, fp32 math) ---
#pragma unroll
      for (int j = 0; j < 8; ++j) {
        const float w = (j < 4) ? ((j == 0) ? w2.x : (j == 1) ? w2.y : (j == 2) ? w2.z : w2.w)
                                : ((j == 4) ? w3.x : (j == 5) ? w3.y : (j == 6) ? w3.z : w3.w);
        float4 mm = h2f(s_m[wv][j][lane]);
        racc.x = fmaf(w, mm.x, racc.x);
        racc.y = fmaf(w, mm.y, racc.y);
        racc.z = fmaf(w, mm.z, racc.z);
        racc.w = fmaf(w, mm.w, racc.w);
        mm.x = fmaf(-w, fmaf(e4.x, mm.x, -a4.x), mm.x);
        mm.y = fmaf(-w, fmaf(e4.y, mm.y, -a4.y), mm.y);
        mm.z = fmaf(-w, fmaf(e4.z, mm.z, -a4.z), mm.z);
        mm.w = fmaf(-w, fmaf(e4.w, mm.w, -a4.w), mm.w);
        s_m[wv][j][lane] = f2h(mm);
      }
      // lane-indexed LDS adds: 64 distinct dword addresses per plane
      atomicAdd(&s_rt[tl][0][lane], racc.x);
      atomicAdd(&s_rt[tl][1][lane], racc.y);
      atomicAdd(&s_rt[tl][2][lane], racc.z);
      atomicAdd(&s_rt[tl][3][lane], racc.w);
    }
    __syncthreads();

    // ---- drain: plain fp16 stores to this chunk's own region ----
    {
      const int tl = tid >> 6, l = tid & 63;  // 16 x 64 = 1024
      const float4 v = make_float4(s_rt[tl][0][l], s_rt[tl][1][l],
                                   s_rt[tl][2][l], s_rt[tl][3][l]);
      *(half4*)(rp + (size_t)(t0 + tl) * DV_ + l * 4) = f2h(v);
    }
    __syncthreads();
  }
}

// ============ kM: MLP head, 2048 blocks x 512 thr ==========================
#define MP_ 64
__global__ __launch_bounds__(512) void kM(const int* __restrict__ concepts,
                                          const float* __restrict__ cemb,
                                          const h16* __restrict__ rpart,
                                          const float* __restrict__ W1,
                                          const float* __restrict__ b1,
                                          const float* __restrict__ W2,
                                          const float* __restrict__ b2,
                                          const float* __restrict__ W3,
                                          const float* __restrict__ b3,
                                          float* __restrict__ out) {
  __shared__ float s_f[MP_][DV_ + DK_];  // 80 KB
  __shared__ h16 s_W1[S_][324];          // 40.5 KB (padded)
  __shared__ float s_h1[8][8][S_];       // 16 KB
  __shared__ int s_c[MP_];
  const int tid = threadIdx.x, g = blockIdx.x;
  const int lane = tid & 63, wv = tid >> 6;
  if (tid < MP_) s_c[tid] = concepts[g * MP_ + tid];
  {
    const int j = tid >> 3, f0 = tid & 7;
    const float4* w1r = (const float4*)(W1 + j * 320);
#pragma unroll
    for (int i = 0; i < 10; ++i) {
      const int k4 = f0 + i * 8;
      *(half4*)&s_W1[j][k4 * 4] = f2h(w1r[k4]);
    }
  }
  __syncthreads();
  {
    const half4* p0 = (const half4*)rpart;
    const half4* p1 = p0 + (size_t)NP_ * 64;
#pragma unroll
    for (int i = 0; i < 8; ++i) {
      const int idx = tid + i * 512, p = idx >> 6, c4 = idx & 63;
      const size_t off = (size_t)(g * MP_ + p) * 64 + c4;
      const float4 v0 = h2f(p0[off]);
      const float4 v1 = h2f(p1[off]);
      *(float4*)&s_f[p][c4 * 4] =
          make_float4(v0.x + v1.x, v0.y + v1.y, v0.z + v1.z, v0.w + v1.w);
    }
    const float4* ce4 = (const float4*)cemb;
    const float4 z = make_float4(0.f, 0.f, 0.f, 0.f);
#pragma unroll
    for (int i = 0; i < 2; ++i) {
      const int idx = tid + i * 512, p = idx >> 4, k4 = idx & 15;
      const int c = s_c[p];
      *(float4*)&s_f[p][DV_ + k4 * 4] = c ? ce4[c * 16 + k4] : z;
    }
  }
  __syncthreads();
  const int j = lane;
  float acc[8];
  {
    const float b1j = b1[j];
#pragma unroll
    for (int p = 0; p < 8; ++p) acc[p] = b1j;
  }
  for (int k4 = 0; k4 < 80; ++k4) {
    const float4 w4 = h2f(*(const half4*)&s_W1[j][k4 * 4]);
#pragma unroll
    for (int p = 0; p < 8; ++p)
      acc[p] += dot4(w4, *(const float4*)&s_f[wv * 8 + p][k4 * 4]);
  }
#pragma unroll
  for (int p = 0; p < 8; ++p) s_h1[wv][p][j] = fmaxf(acc[p], 0.f);
  __syncthreads();
  {
    const float b2j = b2[j];
#pragma unroll
    for (int p = 0; p < 8; ++p) acc[p] = b2j;
  }
  const float4* w2r = (const float4*)(W2 + j * S_);
#pragma unroll
  for (int k4 = 0; k4 < S_ / 4; ++k4) {
    const float4 w4 = w2r[k4];
#pragma unroll
    for (int p = 0; p < 8; ++p)
      acc[p] += dot4(w4, *(const float4*)&s_h1[wv][p][k4 * 4]);
  }
  const float w3j = W3[j], b3v = b3[0];
#pragma unroll
  for (int p = 0; p < 8; ++p) {
    float pp = fmaxf(acc[p], 0.f) * w3j;
    for (int off = 32; off; off >>= 1) pp += __shfl_xor(pp, off, 64);
    if (lane == 0)
      out[g * MP_ + wv * 8 + p] = 1.f / (1.f + expf(-(pp + b3v)));
  }
}

extern "C" void kernel_launch(void* const* d_in, const int* in_sizes, int n_in,
                              void* d_out, int out_size, void* d_ws, size_t ws_size,
                              hipStream_t stream) {
  const int* concepts = (const int*)d_in[0];
  const int* interactions = (const int*)d_in[1];
  const float* Kmem = (const float*)d_in[2];
  const float* Vmem = (const float*)d_in[3];
  const float* cemb = (const float*)d_in[4];
  const float* iemb = (const float*)d_in[5];
  const float* We = (const float*)d_in[6];
  const float* be = (const float*)d_in[7];
  const float* Wa = (const float*)d_in[8];
  const float* ba = (const float*)d_in[9];
  const float* W1 = (const float*)d_in[10];
  const float* b1 = (const float*)d_in[11];
  const float* W2 = (const float*)d_in[12];
  const float* b2 = (const float*)d_in[13];
  const float* W3 = (const float*)d_in[14];
  const float* b3 = (const float*)d_in[15];
  float* out = (float*)d_out;

  const size_t sz_w = (size_t)NCID * N_ * 4;
  const size_t sz_e = (size_t)NIID * DV_ * 4;
  float* wtab = (float*)d_ws;
  float* etab = (float*)((char*)d_ws + sz_w);
  float* atab = (float*)((char*)d_ws + sz_w + sz_e);
  h16* rpart = (h16*)((char*)d_ws + sz_w + 2 * sz_e);  // 2 x 64 MiB

  kW<<<dim3(NCID), dim3(512), 0, stream>>>(Kmem, cemb, wtab);
  kG<<<dim3((NIID + 7) / 8), dim3(512), 0, stream>>>(iemb, We, be, Wa, ba, etab, atab);
  kS<<<dim3(B_ * 2), dim3(1024), 0, stream>>>(concepts, interactions, Vmem,
                                              wtab, etab, atab, rpart);
  kM<<<dim3(NP_ / MP_), dim3(512), 0, stream>>>(concepts, cemb, rpart,
                                                W1, b1, W2, b2, W3, b3, out);
}